// Round 3
// baseline (808.741 us; speedup 1.0000x reference)
//
#include <hip/hip_runtime.h>
#include <math.h>

#define NFEAT 256
#define HID 64
#define NCLS 6
#define CAP 4096  // per-bucket capacity (avg fill 2048 for E=3.2M, n=100K)

// ---------------- utility ----------------

__global__ __launch_bounds__(256) void k_zero_int(int* __restrict__ p, int n) {
  int i = blockIdx.x * 256 + threadIdx.x;
  if (i < n) p[i] = 0;
}

// ---------------- bucket pass: group edges by dst>>6 ----------------
// packed entry = (src << 6) | (dst & 63); src < 2^17, fits 23 bits.

__global__ __launch_bounds__(256) void k_bucket(const int* __restrict__ src,
                                                const int* __restrict__ dst,
                                                int* __restrict__ bcur,
                                                unsigned* __restrict__ packed, int E) {
  int i = blockIdx.x * 256 + threadIdx.x;
  if (i >= E) return;
  int d = dst[i], s = src[i];
  int b = d >> 6;
  int p = atomicAdd(&bcur[b], 1);
  if (p >= CAP) p = CAP - 1;  // statistically unreachable guard
  packed[(size_t)b * CAP + p] = ((unsigned)s << 6) | (unsigned)(d & 63);
}

// ---------------- scan bucket totals -> bucket bases; rowptr[n] = E ----------------
// single block, 256 threads, chunked over nb buckets

__global__ __launch_bounds__(256) void k_scanb(const int* __restrict__ bcur,
                                               int* __restrict__ bbase, int nb,
                                               int* __restrict__ rowptr_n) {
  __shared__ int sh[256];
  __shared__ int carry;
  int t = threadIdx.x;
  if (t == 0) carry = 0;
  __syncthreads();
  for (int base = 0; base < nb; base += 256) {
    int v = (base + t < nb) ? bcur[base + t] : 0;
    sh[t] = v;
    __syncthreads();
    for (int off = 1; off < 256; off <<= 1) {
      int x = sh[t];
      int y = (t >= off) ? sh[t - off] : 0;
      __syncthreads();
      sh[t] = x + y;
      __syncthreads();
    }
    if (base + t < nb) bbase[base + t] = carry + sh[t] - v;
    __syncthreads();
    if (t == 255) carry += sh[255];
    __syncthreads();
  }
  if (t == 0) *rowptr_n = carry;
}

// ---------------- per-bucket counting sort -> srcs, rowptr, dis ----------------
// one block per bucket (64 nodes); sequential srcs writes.

__global__ __launch_bounds__(256) void k_build(const unsigned* __restrict__ packed,
                                               const int* __restrict__ bcur,
                                               const int* __restrict__ bbase,
                                               int* __restrict__ rowptr,
                                               int* __restrict__ srcs,
                                               float* __restrict__ dis, int n) {
  __shared__ int cntl[64];
  __shared__ int offi[64];   // inclusive scan
  __shared__ int offx[64];   // exclusive scan
  int b = blockIdx.x;
  int t = threadIdx.x;
  int m = bcur[b];
  if (m > CAP) m = CAP;
  const unsigned* pb = packed + (size_t)b * CAP;

  if (t < 64) cntl[t] = 0;
  __syncthreads();
  for (int j = t; j < m; j += 256) atomicAdd(&cntl[pb[j] & 63u], 1);
  __syncthreads();
  if (t < 64) offi[t] = cntl[t];
  __syncthreads();
  for (int off = 1; off < 64; off <<= 1) {
    int x = (t < 64) ? offi[t] : 0;
    int y = (t >= off && t < 64) ? offi[t - off] : 0;
    __syncthreads();
    if (t < 64) offi[t] = x + y;
    __syncthreads();
  }
  int bb = bbase[b];
  if (t < 64) {
    offx[t] = offi[t] - cntl[t];
    int v = b * 64 + t;
    if (v < n) {
      rowptr[v] = bb + offx[t];
      dis[v] = rsqrtf((float)cntl[t] + 1.0f);  // +1 self-loop
    }
  }
  __syncthreads();
  if (t < 64) cntl[t] = 0;  // reuse as cursors
  __syncthreads();
  for (int j = t; j < m; j += 256) {
    unsigned e = pb[j];
    int dl = e & 63u;
    int p = atomicAdd(&cntl[dl], 1);
    srcs[bb + offx[dl] + p] = (int)(e >> 6);
  }
}

// ---------------- GEMM: G[row] = dis[row] * (X[row,:] @ W), W is K x 64 ----------------

template<int K>
__global__ __launch_bounds__(256) void k_gemm_scaled(const float* __restrict__ X,
                                                     const float* __restrict__ W,
                                                     const float* __restrict__ dis,
                                                     float* __restrict__ G, int n) {
  __shared__ float Wl[64 * 64];
  __shared__ float Xl[64 * 64];
  const int tid = threadIdx.x;
  const int row0 = blockIdx.x * 64;
  const int tc = tid & 15;
  const int tr = tid >> 4;
  float acc[4][4] = {};

  for (int k0 = 0; k0 < K; k0 += 64) {
    __syncthreads();
#pragma unroll
    for (int i = 0; i < 4; ++i) {
      int idx = tid * 4 + i * 1024;
      int kr = idx >> 6, c = idx & 63;
      *(float4*)&Wl[idx] = *(const float4*)&W[(size_t)(k0 + kr) * 64 + c];
    }
#pragma unroll
    for (int i = 0; i < 4; ++i) {
      int idx = tid * 4 + i * 1024;
      int r = idx >> 6, c = idx & 63;
      int row = row0 + r;
      float4 v = make_float4(0.f, 0.f, 0.f, 0.f);
      if (row < n) v = *(const float4*)&X[(size_t)row * K + k0 + c];
      *(float4*)&Xl[idx] = v;
    }
    __syncthreads();
#pragma unroll 4
    for (int kk = 0; kk < 64; kk += 4) {
      float4 xv[4], wv[4];
#pragma unroll
      for (int r = 0; r < 4; ++r) xv[r] = *(float4*)&Xl[(tr * 4 + r) * 64 + kk];
#pragma unroll
      for (int q = 0; q < 4; ++q) wv[q] = *(float4*)&Wl[(kk + q) * 64 + tc * 4];
#pragma unroll
      for (int r = 0; r < 4; ++r) {
        const float xr[4] = {xv[r].x, xv[r].y, xv[r].z, xv[r].w};
#pragma unroll
        for (int q = 0; q < 4; ++q) {
          acc[r][0] += xr[q] * wv[q].x;
          acc[r][1] += xr[q] * wv[q].y;
          acc[r][2] += xr[q] * wv[q].z;
          acc[r][3] += xr[q] * wv[q].w;
        }
      }
    }
  }
#pragma unroll
  for (int r = 0; r < 4; ++r) {
    int row = row0 + tr * 4 + r;
    if (row < n) {
      float s = dis[row];
      float4 o = make_float4(acc[r][0] * s, acc[r][1] * s, acc[r][2] * s, acc[r][3] * s);
      *(float4*)&G[(size_t)row * 64 + tc * 4] = o;
    }
  }
}

// ---------------- CSR gather-sum + fused finalize ----------------
// out[v] = relu(dis[v] * (sum_{s in N(v)} g[s] + g[v]) + b)

__global__ __launch_bounds__(256) void k_agg_csr(const int* __restrict__ rowptr,
                                                 const int* __restrict__ srcs,
                                                 const float* __restrict__ g,
                                                 const float* __restrict__ dis,
                                                 const float* __restrict__ bias,
                                                 float* __restrict__ outp, int n) {
  int v = blockIdx.x * 16 + (threadIdx.x >> 4);
  if (v >= n) return;
  int lane = threadIdx.x & 15;
  int beg = rowptr[v], end = rowptr[v + 1];
  const float4* g4 = (const float4*)g;
  float4 self = g4[(size_t)v * 16 + lane];
  float ax = self.x, ay = self.y, az = self.z, aw = self.w;

  int j = beg;
  for (; j + 4 <= end; j += 4) {
    int s0 = srcs[j], s1 = srcs[j + 1], s2 = srcs[j + 2], s3 = srcs[j + 3];
    float4 a0 = g4[(size_t)s0 * 16 + lane];
    float4 a1 = g4[(size_t)s1 * 16 + lane];
    float4 a2 = g4[(size_t)s2 * 16 + lane];
    float4 a3 = g4[(size_t)s3 * 16 + lane];
    ax += a0.x + a1.x + a2.x + a3.x;
    ay += a0.y + a1.y + a2.y + a3.y;
    az += a0.z + a1.z + a2.z + a3.z;
    aw += a0.w + a1.w + a2.w + a3.w;
  }
  for (; j < end; ++j) {
    int s0 = srcs[j];
    float4 a0 = g4[(size_t)s0 * 16 + lane];
    ax += a0.x; ay += a0.y; az += a0.z; aw += a0.w;
  }

  float dv = dis[v];
  float4 bb = *(const float4*)&bias[lane * 4];
  float4 o;
  o.x = fmaxf(fmaf(dv, ax, bb.x), 0.f);
  o.y = fmaxf(fmaf(dv, ay, bb.y), 0.f);
  o.z = fmaxf(fmaf(dv, az, bb.z), 0.f);
  o.w = fmaxf(fmaf(dv, aw, bb.w), 0.f);
  ((float4*)outp)[(size_t)v * 16 + lane] = o;
}

// ---------------- final FC: out[row] = A[row,:] @ Wfc + bfc ----------------

__global__ __launch_bounds__(256) void k_fc(const float* __restrict__ A,
                                            const float* __restrict__ Wfc,
                                            const float* __restrict__ bfc,
                                            float* __restrict__ outp, int n) {
  __shared__ float Wl[64 * NCLS];
  __shared__ float bl[8];
  int tid = threadIdx.x;
  for (int i = tid; i < 64 * NCLS; i += 256) Wl[i] = Wfc[i];
  if (tid < NCLS) bl[tid] = bfc[tid];
  __syncthreads();
  int row = blockIdx.x * 256 + tid;
  if (row >= n) return;
  float accv[NCLS];
#pragma unroll
  for (int j = 0; j < NCLS; ++j) accv[j] = bl[j];
  const float4* a4 = (const float4*)&A[(size_t)row * 64];
#pragma unroll
  for (int k4 = 0; k4 < 16; ++k4) {
    float4 a = a4[k4];
    const float av[4] = {a.x, a.y, a.z, a.w};
#pragma unroll
    for (int q = 0; q < 4; ++q)
#pragma unroll
      for (int j = 0; j < NCLS; ++j) accv[j] += av[q] * Wl[(k4 * 4 + q) * NCLS + j];
  }
#pragma unroll
  for (int j = 0; j < NCLS; ++j) outp[(size_t)row * NCLS + j] = accv[j];
}

// ---------------- launch ----------------

extern "C" void kernel_launch(void* const* d_in, const int* in_sizes, int n_in,
                              void* d_out, int out_size, void* d_ws, size_t ws_size,
                              hipStream_t stream) {
  const float* x   = (const float*)d_in[0];
  const int*   ei  = (const int*)d_in[1];
  const float* W1  = (const float*)d_in[2];
  const float* b1  = (const float*)d_in[3];
  const float* W2  = (const float*)d_in[4];
  const float* b2  = (const float*)d_in[5];
  const float* Wfc = (const float*)d_in[6];
  const float* bfc = (const float*)d_in[7];
  float* out = (float*)d_out;

  const int n = in_sizes[0] / NFEAT;   // 100000
  const int E = in_sizes[1] / 2;       // 3200000
  const int* src = ei;
  const int* dst = ei + E;
  const int nbuck = (n + 63) >> 6;     // 1563

  char* ws = (char*)d_ws;
  size_t off = 0;
  auto alloc = [&](size_t bytes) -> void* {
    void* p = (void*)(ws + off);
    off += (bytes + 255) & ~(size_t)255;
    return p;
  };
  float* dis    = (float*)alloc((size_t)n * 4);
  int*   rowptr = (int*)alloc(((size_t)n + 1) * 4);
  int*   srcs   = (int*)alloc((size_t)E * 4);
  int*   bcur   = (int*)alloc((size_t)nbuck * 4);
  int*   bbase  = (int*)alloc((size_t)nbuck * 4);
  // region shared by packed-bucket buffer (build phase) and bufA (layer phase)
  size_t sharedBytes = (size_t)nbuck * CAP * 4;  // 25.6 MB >= n*HID*4
  if ((size_t)n * HID * 4 > sharedBytes) sharedBytes = (size_t)n * HID * 4;
  unsigned* packed = (unsigned*)alloc(sharedBytes);
  float* bufA = (float*)packed;
  float* bufB = (float*)alloc((size_t)n * HID * 4);

  // ---- CSR build (shared by both layers) ----
  k_zero_int<<<(nbuck + 255) / 256, 256, 0, stream>>>(bcur, nbuck);
  k_bucket<<<(E + 255) / 256, 256, 0, stream>>>(src, dst, bcur, packed, E);
  k_scanb<<<1, 256, 0, stream>>>(bcur, bbase, nbuck, rowptr + n);
  k_build<<<nbuck, 256, 0, stream>>>(packed, bcur, bbase, rowptr, srcs, dis, n);

  // ---- layer 1 ----
  k_gemm_scaled<NFEAT><<<(n + 63) / 64, 256, 0, stream>>>(x, W1, dis, bufA, n);
  k_agg_csr<<<(n + 15) / 16, 256, 0, stream>>>(rowptr, srcs, bufA, dis, b1, bufB, n);

  // ---- layer 2 ----
  k_gemm_scaled<HID><<<(n + 63) / 64, 256, 0, stream>>>(bufB, W2, dis, bufA, n);
  k_agg_csr<<<(n + 15) / 16, 256, 0, stream>>>(rowptr, srcs, bufA, dis, b2, bufB, n);

  // ---- FC head ----
  k_fc<<<(n + 255) / 256, 256, 0, stream>>>(bufB, Wfc, bfc, out, n);
}

// Round 4
// 460.065 us; speedup vs baseline: 1.7579x; 1.7579x over previous
//
#include <hip/hip_runtime.h>
#include <math.h>

#define NFEAT 256
#define HID 64
#define NCLS 6
#define NREP 32                 // counter/region replicas (replica = blockIdx&31 -> fixed XCD)
#define SUBCAP 128              // per-replica capacity (mean fill 64, sd 8)
#define CAP (NREP * SUBCAP)     // 4096 entries per bucket (mean 2048)

// ---------------- utility ----------------

__global__ __launch_bounds__(256) void k_zero_int(int* __restrict__ p, int n) {
  int i = blockIdx.x * 256 + threadIdx.x;
  if (i < n) p[i] = 0;
}

// ---------------- bucket pass: group edges by dst>>6, 32-way replicated ----------------
// packed entry = (src << 6) | (dst & 63); src < 2^17 fits.

__global__ __launch_bounds__(256) void k_bucket(const int* __restrict__ src,
                                                const int* __restrict__ dst,
                                                int* __restrict__ bcur,
                                                unsigned* __restrict__ packed,
                                                int E, int nbuck) {
  int i = blockIdx.x * 256 + threadIdx.x;
  if (i >= E) return;
  int r = blockIdx.x & (NREP - 1);
  int d = dst[i], s = src[i];
  int b = d >> 6;
  int p = atomicAdd(&bcur[r * nbuck + b], 1);
  if (p >= SUBCAP) p = SUBCAP - 1;  // statistically unreachable (8+ sd)
  packed[((size_t)b * NREP + r) * SUBCAP + p] = ((unsigned)s << 6) | (unsigned)(d & 63);
}

// ---------------- scan per-bucket totals -> bucket bases; rowptr[n] = E ----------------

__global__ __launch_bounds__(256) void k_scanb(const int* __restrict__ bcur,
                                               int* __restrict__ bbase, int nb,
                                               int* __restrict__ rowptr_n) {
  __shared__ int sh[256];
  __shared__ int carry;
  int t = threadIdx.x;
  if (t == 0) carry = 0;
  __syncthreads();
  for (int base = 0; base < nb; base += 256) {
    int v = 0;
    if (base + t < nb) {
#pragma unroll 8
      for (int r = 0; r < NREP; ++r) {
        int c = bcur[r * nb + base + t];
        v += (c > SUBCAP) ? SUBCAP : c;
      }
    }
    sh[t] = v;
    __syncthreads();
    for (int off = 1; off < 256; off <<= 1) {
      int x = sh[t];
      int y = (t >= off) ? sh[t - off] : 0;
      __syncthreads();
      sh[t] = x + y;
      __syncthreads();
    }
    if (base + t < nb) bbase[base + t] = carry + sh[t] - v;
    __syncthreads();
    if (t == 255) carry += sh[255];
    __syncthreads();
  }
  if (t == 0) *rowptr_n = carry;
}

// ---------------- per-bucket counting sort -> srcs, rowptr, dis ----------------
// one block per bucket (64 nodes); flattened slot loop over NREP sub-regions.

__global__ __launch_bounds__(256) void k_build(const unsigned* __restrict__ packed,
                                               const int* __restrict__ bcur,
                                               const int* __restrict__ bbase,
                                               int* __restrict__ rowptr,
                                               int* __restrict__ srcs,
                                               float* __restrict__ dis,
                                               int n, int nbuck) {
  __shared__ int cntl[64];
  __shared__ int offi[64];
  __shared__ int offx[64];
  __shared__ int cur[64];
  __shared__ int mr[NREP];
  int b = blockIdx.x;
  int t = threadIdx.x;
  if (t < NREP) {
    int c = bcur[t * nbuck + b];
    mr[t] = (c > SUBCAP) ? SUBCAP : c;
  }
  if (t < 64) { cntl[t] = 0; cur[t] = 0; }
  __syncthreads();
  const unsigned* pb = packed + (size_t)b * CAP;

  // histogram over valid slots
  for (int k = t; k < CAP; k += 256) {
    int r = k >> 7, p = k & (SUBCAP - 1);
    if (p < mr[r]) atomicAdd(&cntl[pb[k] & 63u], 1);
  }
  __syncthreads();
  if (t < 64) offi[t] = cntl[t];
  __syncthreads();
  for (int off = 1; off < 64; off <<= 1) {
    int x = (t < 64) ? offi[t] : 0;
    int y = (t >= off && t < 64) ? offi[t - off] : 0;
    __syncthreads();
    if (t < 64) offi[t] = x + y;
    __syncthreads();
  }
  int bb = bbase[b];
  if (t < 64) {
    offx[t] = offi[t] - cntl[t];
    int v = b * 64 + t;
    if (v < n) {
      rowptr[v] = bb + offx[t];
      dis[v] = rsqrtf((float)cntl[t] + 1.0f);  // +1 self-loop
    }
  }
  __syncthreads();
  // scatter (stable order not required; fp sum order arbitrary)
  for (int k = t; k < CAP; k += 256) {
    int r = k >> 7, p = k & (SUBCAP - 1);
    if (p < mr[r]) {
      unsigned e = pb[k];
      int dl = e & 63u;
      int q = atomicAdd(&cur[dl], 1);
      srcs[bb + offx[dl] + q] = (int)(e >> 6);
    }
  }
}

// ---------------- GEMM: G[row] = dis[row] * (X[row,:] @ W), W is K x 64 ----------------

template<int K>
__global__ __launch_bounds__(256) void k_gemm_scaled(const float* __restrict__ X,
                                                     const float* __restrict__ W,
                                                     const float* __restrict__ dis,
                                                     float* __restrict__ G, int n) {
  __shared__ float Wl[64 * 64];
  __shared__ float Xl[64 * 64];
  const int tid = threadIdx.x;
  const int row0 = blockIdx.x * 64;
  const int tc = tid & 15;
  const int tr = tid >> 4;
  float acc[4][4] = {};

  for (int k0 = 0; k0 < K; k0 += 64) {
    __syncthreads();
#pragma unroll
    for (int i = 0; i < 4; ++i) {
      int idx = tid * 4 + i * 1024;
      int kr = idx >> 6, c = idx & 63;
      *(float4*)&Wl[idx] = *(const float4*)&W[(size_t)(k0 + kr) * 64 + c];
    }
#pragma unroll
    for (int i = 0; i < 4; ++i) {
      int idx = tid * 4 + i * 1024;
      int r = idx >> 6, c = idx & 63;
      int row = row0 + r;
      float4 v = make_float4(0.f, 0.f, 0.f, 0.f);
      if (row < n) v = *(const float4*)&X[(size_t)row * K + k0 + c];
      *(float4*)&Xl[idx] = v;
    }
    __syncthreads();
#pragma unroll 4
    for (int kk = 0; kk < 64; kk += 4) {
      float4 xv[4], wv[4];
#pragma unroll
      for (int r = 0; r < 4; ++r) xv[r] = *(float4*)&Xl[(tr * 4 + r) * 64 + kk];
#pragma unroll
      for (int q = 0; q < 4; ++q) wv[q] = *(float4*)&Wl[(kk + q) * 64 + tc * 4];
#pragma unroll
      for (int r = 0; r < 4; ++r) {
        const float xr[4] = {xv[r].x, xv[r].y, xv[r].z, xv[r].w};
#pragma unroll
        for (int q = 0; q < 4; ++q) {
          acc[r][0] += xr[q] * wv[q].x;
          acc[r][1] += xr[q] * wv[q].y;
          acc[r][2] += xr[q] * wv[q].z;
          acc[r][3] += xr[q] * wv[q].w;
        }
      }
    }
  }
#pragma unroll
  for (int r = 0; r < 4; ++r) {
    int row = row0 + tr * 4 + r;
    if (row < n) {
      float s = dis[row];
      float4 o = make_float4(acc[r][0] * s, acc[r][1] * s, acc[r][2] * s, acc[r][3] * s);
      *(float4*)&G[(size_t)row * 64 + tc * 4] = o;
    }
  }
}

// ---------------- CSR gather-sum + fused finalize ----------------
// out[v] = relu(dis[v] * (sum_{s in N(v)} g[s] + g[v]) + b)

__global__ __launch_bounds__(256) void k_agg_csr(const int* __restrict__ rowptr,
                                                 const int* __restrict__ srcs,
                                                 const float* __restrict__ g,
                                                 const float* __restrict__ dis,
                                                 const float* __restrict__ bias,
                                                 float* __restrict__ outp, int n) {
  int v = blockIdx.x * 16 + (threadIdx.x >> 4);
  if (v >= n) return;
  int lane = threadIdx.x & 15;
  int beg = rowptr[v], end = rowptr[v + 1];
  const float4* g4 = (const float4*)g;
  float4 self = g4[(size_t)v * 16 + lane];
  float ax = self.x, ay = self.y, az = self.z, aw = self.w;

  int j = beg;
  for (; j + 4 <= end; j += 4) {
    int s0 = srcs[j], s1 = srcs[j + 1], s2 = srcs[j + 2], s3 = srcs[j + 3];
    float4 a0 = g4[(size_t)s0 * 16 + lane];
    float4 a1 = g4[(size_t)s1 * 16 + lane];
    float4 a2 = g4[(size_t)s2 * 16 + lane];
    float4 a3 = g4[(size_t)s3 * 16 + lane];
    ax += a0.x + a1.x + a2.x + a3.x;
    ay += a0.y + a1.y + a2.y + a3.y;
    az += a0.z + a1.z + a2.z + a3.z;
    aw += a0.w + a1.w + a2.w + a3.w;
  }
  for (; j < end; ++j) {
    int s0 = srcs[j];
    float4 a0 = g4[(size_t)s0 * 16 + lane];
    ax += a0.x; ay += a0.y; az += a0.z; aw += a0.w;
  }

  float dv = dis[v];
  float4 bb = *(const float4*)&bias[lane * 4];
  float4 o;
  o.x = fmaxf(fmaf(dv, ax, bb.x), 0.f);
  o.y = fmaxf(fmaf(dv, ay, bb.y), 0.f);
  o.z = fmaxf(fmaf(dv, az, bb.z), 0.f);
  o.w = fmaxf(fmaf(dv, aw, bb.w), 0.f);
  ((float4*)outp)[(size_t)v * 16 + lane] = o;
}

// ---------------- final FC: out[row] = A[row,:] @ Wfc + bfc ----------------

__global__ __launch_bounds__(256) void k_fc(const float* __restrict__ A,
                                            const float* __restrict__ Wfc,
                                            const float* __restrict__ bfc,
                                            float* __restrict__ outp, int n) {
  __shared__ float Wl[64 * NCLS];
  __shared__ float bl[8];
  int tid = threadIdx.x;
  for (int i = tid; i < 64 * NCLS; i += 256) Wl[i] = Wfc[i];
  if (tid < NCLS) bl[tid] = bfc[tid];
  __syncthreads();
  int row = blockIdx.x * 256 + tid;
  if (row >= n) return;
  float accv[NCLS];
#pragma unroll
  for (int j = 0; j < NCLS; ++j) accv[j] = bl[j];
  const float4* a4 = (const float4*)&A[(size_t)row * 64];
#pragma unroll
  for (int k4 = 0; k4 < 16; ++k4) {
    float4 a = a4[k4];
    const float av[4] = {a.x, a.y, a.z, a.w};
#pragma unroll
    for (int q = 0; q < 4; ++q)
#pragma unroll
      for (int j = 0; j < NCLS; ++j) accv[j] += av[q] * Wl[(k4 * 4 + q) * NCLS + j];
  }
#pragma unroll
  for (int j = 0; j < NCLS; ++j) outp[(size_t)row * NCLS + j] = accv[j];
}

// ---------------- launch ----------------

extern "C" void kernel_launch(void* const* d_in, const int* in_sizes, int n_in,
                              void* d_out, int out_size, void* d_ws, size_t ws_size,
                              hipStream_t stream) {
  const float* x   = (const float*)d_in[0];
  const int*   ei  = (const int*)d_in[1];
  const float* W1  = (const float*)d_in[2];
  const float* b1  = (const float*)d_in[3];
  const float* W2  = (const float*)d_in[4];
  const float* b2  = (const float*)d_in[5];
  const float* Wfc = (const float*)d_in[6];
  const float* bfc = (const float*)d_in[7];
  float* out = (float*)d_out;

  const int n = in_sizes[0] / NFEAT;   // 100000
  const int E = in_sizes[1] / 2;       // 3200000
  const int* src = ei;
  const int* dst = ei + E;
  const int nbuck = (n + 63) >> 6;     // 1563

  char* ws = (char*)d_ws;
  size_t off = 0;
  auto alloc = [&](size_t bytes) -> void* {
    void* p = (void*)(ws + off);
    off += (bytes + 255) & ~(size_t)255;
    return p;
  };
  float* dis    = (float*)alloc((size_t)n * 4);
  int*   rowptr = (int*)alloc(((size_t)n + 1) * 4);
  int*   srcs   = (int*)alloc((size_t)E * 4);
  int*   bcur   = (int*)alloc((size_t)nbuck * NREP * 4);
  int*   bbase  = (int*)alloc((size_t)nbuck * 4);
  // region shared by packed-bucket buffer (build phase) and bufA (layer phase)
  size_t sharedBytes = (size_t)nbuck * CAP * 4;  // 25.6 MB >= n*HID*4
  if ((size_t)n * HID * 4 > sharedBytes) sharedBytes = (size_t)n * HID * 4;
  unsigned* packed = (unsigned*)alloc(sharedBytes);
  float* bufA = (float*)packed;
  float* bufB = (float*)alloc((size_t)n * HID * 4);

  // ---- CSR build (shared by both layers) ----
  k_zero_int<<<(nbuck * NREP + 255) / 256, 256, 0, stream>>>(bcur, nbuck * NREP);
  k_bucket<<<(E + 255) / 256, 256, 0, stream>>>(src, dst, bcur, packed, E, nbuck);
  k_scanb<<<1, 256, 0, stream>>>(bcur, bbase, nbuck, rowptr + n);
  k_build<<<nbuck, 256, 0, stream>>>(packed, bcur, bbase, rowptr, srcs, dis, n, nbuck);

  // ---- layer 1 ----
  k_gemm_scaled<NFEAT><<<(n + 63) / 64, 256, 0, stream>>>(x, W1, dis, bufA, n);
  k_agg_csr<<<(n + 15) / 16, 256, 0, stream>>>(rowptr, srcs, bufA, dis, b1, bufB, n);

  // ---- layer 2 ----
  k_gemm_scaled<HID><<<(n + 63) / 64, 256, 0, stream>>>(bufB, W2, dis, bufA, n);
  k_agg_csr<<<(n + 15) / 16, 256, 0, stream>>>(rowptr, srcs, bufA, dis, b2, bufB, n);

  // ---- FC head ----
  k_fc<<<(n + 255) / 256, 256, 0, stream>>>(bufB, Wfc, bfc, out, n);
}